// Round 2
// baseline (547.134 us; speedup 1.0000x reference)
//
#include <hip/hip_runtime.h>
#include <hip/hip_bf16.h>
#include <math.h>
#include <stdint.h>

// Problem constants (fixed by the reference)
#define S_LEN  8192
#define DMODEL 512
#define NBATCH 4

// gemm_m tiling: 256x256 tile, 512 threads (8 waves as 2x4 of 128x64 subtiles)
constexpr int TM = 256, TN = 256, BK = 32;
constexpr int PK = 40;                    // padded LDS row stride (shorts); 80 B, 16B-aligned

// gemm_c tiling
constexpr int CBK = 32;
constexpr int PKC = 40;

// Workspace layout (bytes):
//   Mred @ 0    : 4 MB   (4 x 512 x 512 f32)  -- atomically accumulated
//   vws  @ 4MB  : 8 KB   (4 x 512 f32)        -- atomically accumulated
constexpr size_t MRED_OFF = 0;
constexpr size_t VWS_OFF  = (size_t)NBATCH * DMODEL * DMODEL * 4;   // 4 MB

typedef short bfrag  __attribute__((ext_vector_type(8)));   // 8 bf16 (4 VGPRs)
typedef float facc   __attribute__((ext_vector_type(4)));   // 4 fp32 acc

__device__ __forceinline__ unsigned pk2(float a, float b) {
  __hip_bfloat162 t = __float22bfloat162_rn(make_float2(a, b));  // v_cvt_pk_bf16_f32
  union { __hip_bfloat162 h; unsigned u; } cc; cc.h = t; return cc.u;
}

__device__ __forceinline__ void atomAddF(float* p, float v) {
  unsafeAtomicAdd(p, v);   // global_atomic_add_f32, no return
}

__device__ __forceinline__ float selc(const float4& v, int c) {
  return c == 0 ? v.x : c == 1 ? v.y : c == 2 ? v.z : v.w;
}

// ---------------------------------------------------------------------------
// Kernel 1: M[b][d'][d] += sum_{t in chunk} w_t h[b][t][d'] e[b][t][d]
//
// R2: R0/R1 both showed MfmaUtil~9%, VALUBusy~13%, HBM<40%, Occ~18% -- a
// latency-bound signature at 1 block/CU (8 waves, one barrier domain: when
// all waves rendezvous, the CU issues nothing). Fix = TLP: NS=32 -> grid 512
// = 2 independent blocks/CU (LDS 2x40KB=80KB, VGPR 116 fits 4 waves/SIMD).
// Partials for NS=32 would need 128MB ws, so accumulate straight into Mred
// with fp32 atomics (4MB, memset first) -- this also deletes the reduce
// kernel (-64MB partial writes, -68MB reads, -1 launch). XCD swizzle groups
// each tile-position's 32 kt-blocks on one XCD: atomics land in that XCD's
// L2 (256KB hot region), and the XCD's two positions share the same h-panel
// (read locality, R1-verified FETCH 131->71MB). Loop structure reverts to
// the R0-proven two-__syncthreads form (one change at a time).
// ---------------------------------------------------------------------------
template <int NS>
__global__ __launch_bounds__(512, 4) void gemm_m_kernel(
    const float* __restrict__ h, const float* __restrict__ e,
    float* __restrict__ Mout, float* __restrict__ vout)
{
  __shared__ short Al[TM * PK];   // 20 KB
  __shared__ short Bl[TN * PK];   // 20 KB

  constexpr int KCH = S_LEN / NS;          // 256 for NS=32

  // XCD-grouped bijective swizzle. grid = 16 * NS (=512 for NS=32).
  // Dispatcher round-robins blockIdx%8 across XCDs; we invert so that tile
  // position p = xcd*2 + ph gets all its NS kt-chunks on one XCD.
  const int sidx = blockIdx.x;
  const int xcd  = sidx & 7;
  const int m0   = sidx >> 3;              // 0 .. 2*NS-1
  const int ph   = m0 / NS;                // 0/1: which of the XCD's 2 positions
  const int kt   = m0 % NS;
  const int p    = xcd * 2 + ph;           // tile position 0..15
  const int bb   = p >> 2;
  const int mt   = (p >> 1) & 1;           // p,p^1 share (bb,mt) => shared h-panel
  const int nt   = p & 1;

  const int tid   = threadIdx.x;
  const bool isB  = (tid >= 256);      // wave-uniform (waves 4..7)
  const int hid   = tid & 255;
  const int col4  = (hid >> 2) * 4;    // 0..252 within the 256-wide tile
  const int trow  = hid & 3;           // t-rows trow*8 .. trow*8+7

  const int wv   = tid >> 6;           // 8 waves -> 2x4 of 128x64 subtiles
  const int wm   = wv >> 2;            // 0..1 (row half)
  const int wn   = wv & 3;             // 0..3 (col quarter)
  const int lane = tid & 63;
  const int lm   = lane & 15, q = lane >> 4;

  const float* src = (isB ? e : h) + (size_t)bb * S_LEN * DMODEL
                   + (isB ? nt * TN : mt * TM) + col4;
  short* ldst = (isB ? Bl : Al) + col4 * PK + trow * 8;

  facc acc[8][4];
#pragma unroll
  for (int i = 0; i < 8; ++i)
#pragma unroll
    for (int j = 0; j < 4; ++j) acc[i][j] = (facc){0.f, 0.f, 0.f, 0.f};

  const float lnA = -(float)M_PI / (float)S_LEN;   // log(alpha), negative
  const int tstart = kt * KCH, tend = tstart + KCH;

  float wbase = __expf(lnA * (float)(S_LEN - 1 - tstart - trow * 8));
  const float stepw = __expf(-lnA * (float)BK);    // alpha^(-32)
  float cr[8];
#pragma unroll
  for (int r = 0; r < 8; ++r)
    cr[r] = __expf(-lnA * (float)r);               // alpha^(-r)

  float4 vacc4 = {0.f, 0.f, 0.f, 0.f};

  // ---- preload iter 0 ----
  float4 cur[8];
  {
    const float* p0 = src + (size_t)(tstart + trow * 8) * DMODEL;
#pragma unroll
    for (int r = 0; r < 8; ++r) cur[r] = *(const float4*)(p0 + (size_t)r * DMODEL);
  }

  for (int t0 = tstart; t0 < tend; t0 += BK) {
    // ---- scale (B only) + v accumulate ----
    if (isB) {
#pragma unroll
      for (int r = 0; r < 8; ++r) {
        const float w = wbase * cr[r];
        cur[r].x *= w; cur[r].y *= w; cur[r].z *= w; cur[r].w *= w;
      }
      if (mt == 0) {
#pragma unroll
        for (int r = 0; r < 8; ++r) {
          vacc4.x += cur[r].x; vacc4.y += cur[r].y;
          vacc4.z += cur[r].z; vacc4.w += cur[r].w;
        }
      }
    }
    wbase *= stepw;

    // ---- packed bf16 convert + register transpose (frees cur) ----
    uint4 pk[4];
#pragma unroll
    for (int c = 0; c < 4; ++c) {
      pk[c].x = pk2(selc(cur[0], c), selc(cur[1], c));
      pk[c].y = pk2(selc(cur[2], c), selc(cur[3], c));
      pk[c].z = pk2(selc(cur[4], c), selc(cur[5], c));
      pk[c].w = pk2(selc(cur[6], c), selc(cur[7], c));
    }

    // ---- issue next tile's loads (prefetch distance ~= one iteration) ----
    if (t0 + BK < tend) {
      const float* p0 = src + (size_t)(t0 + BK + trow * 8) * DMODEL;
#pragma unroll
      for (int r = 0; r < 8; ++r) cur[r] = *(const float4*)(p0 + (size_t)r * DMODEL);
    }

    __syncthreads();   // previous iteration's frag reads done
#pragma unroll
    for (int c = 0; c < 4; ++c)
      *(uint4*)(ldst + c * PK) = pk[c];
    __syncthreads();

    bfrag af[8], bf[4];
#pragma unroll
    for (int i = 0; i < 8; ++i)
      af[i] = *(const bfrag*)&Al[(wm * 128 + i * 16 + lm) * PK + q * 8];
#pragma unroll
    for (int j = 0; j < 4; ++j)
      bf[j] = *(const bfrag*)&Bl[(wn * 64 + j * 16 + lm) * PK + q * 8];
#pragma unroll
    for (int i = 0; i < 8; ++i)
#pragma unroll
      for (int j = 0; j < 4; ++j)
        acc[i][j] = __builtin_amdgcn_mfma_f32_16x16x32_bf16(af[i], bf[j], acc[i][j], 0, 0, 0);
  }

  // ---- atomic accumulation into Mred (XCD-local L2) ----
  float* Mb = Mout + (size_t)bb * DMODEL * DMODEL;
#pragma unroll
  for (int i = 0; i < 8; ++i)
#pragma unroll
    for (int j = 0; j < 4; ++j)
#pragma unroll
      for (int r = 0; r < 4; ++r) {
        const int row = mt * TM + wm * 128 + i * 16 + q * 4 + r;
        const int col = nt * TN + wn * 64 + j * 16 + lm;
        atomAddF(&Mb[(size_t)row * DMODEL + col], acc[i][j][r]);
      }
  if (isB && mt == 0) {
    float* vp = &vout[bb * DMODEL + nt * TN + col4];
    atomAddF(vp + 0, vacc4.x); atomAddF(vp + 1, vacc4.y);
    atomAddF(vp + 2, vacc4.z); atomAddF(vp + 3, vacc4.w);
  }
}

// ---------------------------------------------------------------------------
// Kernel 2: C[b][s][d] = sum_{d'} W[s][d'] Mred[b][d'][d] + bias[s]*v[b][d]
// 64x64 tiles, K=512, 16 pipelined iters, plain stores. (Unchanged.)
// ---------------------------------------------------------------------------
__global__ __launch_bounds__(256) void gemm_c_kernel(
    const float* __restrict__ Wmat, const float* __restrict__ bias,
    const float* __restrict__ Mred, const float* __restrict__ vws,
    float* __restrict__ out)
{
  __shared__ short Wl[64 * PKC];
  __shared__ short Ml[64 * PKC];

  const int blk = blockIdx.x;          // grid = 4 * 8 * 8 = 256
  const int ntc = blk & 7;
  const int mtc = (blk >> 3) & 7;
  const int bb  = blk >> 6;

  const int tid  = threadIdx.x;
  const bool isM = (tid >= 128);
  const int hid  = tid & 127;
  const int arow = hid & 63;           // W-half
  const int ahalf = (hid >> 6) * 16;
  const int mcol4 = (hid & 15) * 4;    // M-half
  const int mrow4 = (hid >> 4) * 4;

  const int wv   = tid >> 6;
  const int lane = tid & 63;
  const int lm   = lane & 15, q = lane >> 4;

  const float* Mb = Mred + (size_t)bb * DMODEL * DMODEL;

  facc acc[4];
#pragma unroll
  for (int j = 0; j < 4; ++j) acc[j] = (facc){0.f, 0.f, 0.f, 0.f};

  float4 cur[4];
  if (!isM) {
    const float* p = &Wmat[(size_t)(mtc * 64 + arow) * DMODEL + ahalf];
#pragma unroll
    for (int r = 0; r < 4; ++r) cur[r] = *(const float4*)(p + r * 4);
  } else {
    const float* p = Mb + (size_t)mrow4 * DMODEL + ntc * 64 + mcol4;
#pragma unroll
    for (int r = 0; r < 4; ++r) cur[r] = *(const float4*)(p + (size_t)r * DMODEL);
  }

  for (int k0 = 0; k0 < DMODEL; k0 += CBK) {
    uint4 pw0, pw1;
    uint2 pm[4];
    if (!isM) {
      pw0.x = pk2(cur[0].x, cur[0].y); pw0.y = pk2(cur[0].z, cur[0].w);
      pw0.z = pk2(cur[1].x, cur[1].y); pw0.w = pk2(cur[1].z, cur[1].w);
      pw1.x = pk2(cur[2].x, cur[2].y); pw1.y = pk2(cur[2].z, cur[2].w);
      pw1.z = pk2(cur[3].x, cur[3].y); pw1.w = pk2(cur[3].z, cur[3].w);
    } else {
#pragma unroll
      for (int c = 0; c < 4; ++c) {
        pm[c].x = pk2(selc(cur[0], c), selc(cur[1], c));
        pm[c].y = pk2(selc(cur[2], c), selc(cur[3], c));
      }
    }

    if (k0 + CBK < DMODEL) {
      if (!isM) {
        const float* p = &Wmat[(size_t)(mtc * 64 + arow) * DMODEL + k0 + CBK + ahalf];
#pragma unroll
        for (int r = 0; r < 4; ++r) cur[r] = *(const float4*)(p + r * 4);
      } else {
        const float* p = Mb + (size_t)(k0 + CBK + mrow4) * DMODEL + ntc * 64 + mcol4;
#pragma unroll
        for (int r = 0; r < 4; ++r) cur[r] = *(const float4*)(p + (size_t)r * DMODEL);
      }
    }

    __syncthreads();
    if (!isM) {
      *(uint4*)&Wl[arow * PKC + ahalf]     = pw0;
      *(uint4*)&Wl[arow * PKC + ahalf + 8] = pw1;
    } else {
#pragma unroll
      for (int c = 0; c < 4; ++c)
        *(uint2*)&Ml[(mcol4 + c) * PKC + mrow4] = pm[c];
    }
    __syncthreads();

    bfrag af, bf[4];
    af = *(const bfrag*)&Wl[(wv * 16 + lm) * PKC + q * 8];
#pragma unroll
    for (int j = 0; j < 4; ++j)
      bf[j] = *(const bfrag*)&Ml[(j * 16 + lm) * PKC + q * 8];
#pragma unroll
    for (int j = 0; j < 4; ++j)
      acc[j] = __builtin_amdgcn_mfma_f32_16x16x32_bf16(af, bf[j], acc[j], 0, 0, 0);
  }

#pragma unroll
  for (int j = 0; j < 4; ++j)
#pragma unroll
    for (int r = 0; r < 4; ++r) {
      const int row = mtc * 64 + wv * 16 + q * 4 + r;   // s
      const int col = ntc * 64 + j * 16 + lm;           // d
      out[((size_t)bb * DMODEL + row) * DMODEL + col] =
          acc[j][r] + bias[row] * vws[bb * DMODEL + col];
    }
}

// ---------------------------------------------------------------------------
extern "C" void kernel_launch(void* const* d_in, const int* in_sizes, int n_in,
                              void* d_out, int out_size, void* d_ws, size_t ws_size,
                              hipStream_t stream) {
  const float* h    = (const float*)d_in[0];   // (4, 8192, 512) fp32
  const float* e    = (const float*)d_in[1];   // (4, 8192, 512) fp32
  const float* Wmat = (const float*)d_in[2];   // (512, 512) fp32
  const float* bias = (const float*)d_in[3];   // (512,) fp32
  float* out = (float*)d_out;                  // (4, 512, 512) fp32

  float* Mred = (float*)((char*)d_ws + MRED_OFF);
  float* vws  = (float*)((char*)d_ws + VWS_OFF);

  // zero the 4MB+8KB accumulators (stays hot in L2/L3)
  hipMemsetAsync(d_ws, 0, VWS_OFF + (size_t)NBATCH * DMODEL * 4, stream);

  constexpr int NS = 32;                       // grid 512 = 2 blocks/CU
  gemm_m_kernel<NS><<<16 * NS, 512, 0, stream>>>(h, e, Mred, vws);
  gemm_c_kernel<<<NBATCH * 64, 256, 0, stream>>>(Wmat, bias, Mred, vws, out);
}

// Round 3
// 209.922 us; speedup vs baseline: 2.6064x; 2.6064x over previous
//
#include <hip/hip_runtime.h>
#include <hip/hip_bf16.h>
#include <math.h>
#include <stdint.h>

// Problem constants (fixed by the reference)
#define S_LEN  8192
#define DMODEL 512
#define NBATCH 4

// gemm_m tiling: 256x128 tile, 512 threads (8 waves as 4x2 of 64x64 subtiles).
// R3: tile split 256x256 -> 2x 256x128 doubles grid to 512 = 2 blocks/CU
// (TLP to cover barrier rendezvous), halves per-wave acc to 64 regs so both
// blocks are resident WITHOUT touching launch_bounds (R2 lesson: the 2nd
// launch_bounds arg acts as blocks/CU -> reg cap -> spill catastrophe).
constexpr int TM = 256, TN = 128, BK = 32;
constexpr int PK = 40;                    // padded LDS row stride (shorts); 80 B, 16B-aligned

// gemm_c tiling
constexpr int CBK = 32;
constexpr int PKC = 40;

// Workspace layout (bytes):
//   Mred  @ 0          : 4 MB   (4 x 512 x 512 f32)
//   vws   @ 4MB        : 8 KB   (4 x 512 f32)
//   Mpart @ 4MB+8KB    : NBATCH*NS*8 tiles x 128 KB  (NS=16: 64 MB)
//   vpart @ after Mpart: NS*NBATCH rows x 2 KB
constexpr size_t MRED_OFF  = 0;
constexpr size_t VWS_OFF   = (size_t)NBATCH * DMODEL * DMODEL * 4;          // 4 MB
constexpr size_t MPART_OFF = VWS_OFF + (size_t)NBATCH * DMODEL * 4;         // +8 KB

__host__ __device__ constexpr size_t mpart_elems(int ns) {
  return (size_t)NBATCH * ns * 8 * (TM * TN);
}
__host__ __device__ constexpr size_t vpart_elems(int ns) {
  return (size_t)ns * NBATCH * DMODEL;
}
__host__ __device__ constexpr size_t ws_need(int ns) {
  return MPART_OFF + (mpart_elems(ns) + vpart_elems(ns)) * 4;   // 71.35 MB @ NS=16
}

typedef short bfrag  __attribute__((ext_vector_type(8)));   // 8 bf16 (4 VGPRs)
typedef float facc   __attribute__((ext_vector_type(4)));   // 4 fp32 acc

__device__ __forceinline__ unsigned pk2(float a, float b) {
  __hip_bfloat162 t = __float22bfloat162_rn(make_float2(a, b));  // v_cvt_pk_bf16_f32
  union { __hip_bfloat162 h; unsigned u; } cc; cc.h = t; return cc.u;
}

__device__ __forceinline__ void atomAddF(float* p, float v) {
  unsafeAtomicAdd(p, v);
}

__device__ __forceinline__ float selc(const float4& v, int c) {
  return c == 0 ? v.x : c == 1 ? v.y : c == 2 ? v.z : v.w;
}

// ---------------------------------------------------------------------------
// Kernel 1: partial M[b][d'][d] = sum_{t in chunk} w_t h[b][t][d'] e[b][t][d]
// 256x128 tiles. Waves 0-3 stage A (h: 256 cols x 32 t, 8 t-rows/thread),
// waves 4-7 stage B (e: 128 cols x 32 t, 4 t-rows/thread). Register-prefetch
// pipeline + packed bf16 convert, R0-proven two-barrier loop. 8 waves as
// 4x2 grid of 64x64 subtiles -> acc[4][4] (64 regs/wave): VGPR ~110 + 64
// acc both <=128 -> 4 waves/SIMD -> 2 blocks/CU resident.
// ---------------------------------------------------------------------------
template <int NS, bool ATOMIC>
__global__ __launch_bounds__(512, 2) void gemm_m_kernel(
    const float* __restrict__ h, const float* __restrict__ e,
    float* __restrict__ Mout, float* __restrict__ vout)
{
  __shared__ short Al[TM * PK];   // 20 KB
  __shared__ short Bl[TN * PK];   // 10 KB

  constexpr int KCH = S_LEN / NS;

  const int blk = blockIdx.x;          // grid = NBATCH * NS * 8
  const int pos = blk & 7;             // mt*4 + nt
  const int kt  = (blk >> 3) % NS;
  const int bb  = blk / (8 * NS);
  const int mt  = pos >> 2;            // 0..1 (256-row half)
  const int nt  = pos & 3;             // 0..3 (128-col quarter)

  const int tid  = threadIdx.x;
  const bool isB = (tid >= 256);       // wave-uniform (waves 4..7)
  const int hid  = tid & 255;
  const int colA = (hid >> 2) * 4;     // A: 0..252
  const int trA  = hid & 3;            // A: t-rows trA*8 .. +8
  const int colB = (hid >> 3) * 4;     // B: 0..124
  const int trB  = hid & 7;            // B: t-rows trB*4 .. +4

  const int wv   = tid >> 6;           // 8 waves -> 4x2 of 64x64 subtiles
  const int wm   = wv >> 1;            // 0..3 (row quarter)
  const int wn   = wv & 1;             // 0..1 (col half)
  const int lane = tid & 63;
  const int lm   = lane & 15, q = lane >> 4;

  const float* src = isB
      ? e + (size_t)bb * S_LEN * DMODEL + nt * TN + colB
      : h + (size_t)bb * S_LEN * DMODEL + mt * TM + colA;
  short* ldst = isB ? (Bl + colB * PK + trB * 4)
                    : (Al + colA * PK + trA * 8);
  const int tr0 = isB ? trB * 4 : trA * 8;   // first t-row this thread stages

  facc acc[4][4];
#pragma unroll
  for (int i = 0; i < 4; ++i)
#pragma unroll
    for (int j = 0; j < 4; ++j) acc[i][j] = (facc){0.f, 0.f, 0.f, 0.f};

  const float lnA = -(float)M_PI / (float)S_LEN;   // log(alpha), negative
  const int tstart = kt * KCH, tend = tstart + KCH;

  float wbase = __expf(lnA * (float)(S_LEN - 1 - tstart - trB * 4));
  const float stepw = __expf(-lnA * (float)BK);    // alpha^(-32)
  float cr[4];
#pragma unroll
  for (int r = 0; r < 4; ++r)
    cr[r] = __expf(-lnA * (float)r);               // alpha^(-r)

  float4 vacc4 = {0.f, 0.f, 0.f, 0.f};

  // ---- preload iter 0 ----
  float4 cur[8];
  {
    const float* p0 = src + (size_t)(tstart + tr0) * DMODEL;
    if (!isB) {
#pragma unroll
      for (int r = 0; r < 8; ++r) cur[r] = *(const float4*)(p0 + (size_t)r * DMODEL);
    } else {
#pragma unroll
      for (int r = 0; r < 4; ++r) cur[r] = *(const float4*)(p0 + (size_t)r * DMODEL);
    }
  }

  for (int t0 = tstart; t0 < tend; t0 += BK) {
    // ---- scale (B only) + v accumulate ----
    if (isB) {
#pragma unroll
      for (int r = 0; r < 4; ++r) {
        const float w = wbase * cr[r];
        cur[r].x *= w; cur[r].y *= w; cur[r].z *= w; cur[r].w *= w;
      }
      if (mt == 0) {
#pragma unroll
        for (int r = 0; r < 4; ++r) {
          vacc4.x += cur[r].x; vacc4.y += cur[r].y;
          vacc4.z += cur[r].z; vacc4.w += cur[r].w;
        }
      }
      wbase *= stepw;
    }

    // ---- packed bf16 convert + register transpose (frees cur) ----
    uint4 pk[4];
    if (!isB) {
#pragma unroll
      for (int c = 0; c < 4; ++c) {
        pk[c].x = pk2(selc(cur[0], c), selc(cur[1], c));
        pk[c].y = pk2(selc(cur[2], c), selc(cur[3], c));
        pk[c].z = pk2(selc(cur[4], c), selc(cur[5], c));
        pk[c].w = pk2(selc(cur[6], c), selc(cur[7], c));
      }
    } else {
#pragma unroll
      for (int c = 0; c < 4; ++c) {
        pk[c].x = pk2(selc(cur[0], c), selc(cur[1], c));
        pk[c].y = pk2(selc(cur[2], c), selc(cur[3], c));
      }
    }

    // ---- issue next tile's loads (prefetch distance ~= one iteration) ----
    if (t0 + BK < tend) {
      const float* p0 = src + (size_t)(t0 + BK + tr0) * DMODEL;
      if (!isB) {
#pragma unroll
        for (int r = 0; r < 8; ++r) cur[r] = *(const float4*)(p0 + (size_t)r * DMODEL);
      } else {
#pragma unroll
        for (int r = 0; r < 4; ++r) cur[r] = *(const float4*)(p0 + (size_t)r * DMODEL);
      }
    }

    __syncthreads();   // previous iteration's frag reads done
    if (!isB) {
#pragma unroll
      for (int c = 0; c < 4; ++c)
        *(uint4*)(ldst + c * PK) = pk[c];
    } else {
#pragma unroll
      for (int c = 0; c < 4; ++c) {
        uint2 t2; t2.x = pk[c].x; t2.y = pk[c].y;
        *(uint2*)(ldst + c * PK) = t2;
      }
    }
    __syncthreads();

    bfrag af[4], bf[4];
#pragma unroll
    for (int i = 0; i < 4; ++i)
      af[i] = *(const bfrag*)&Al[(wm * 64 + i * 16 + lm) * PK + q * 8];
#pragma unroll
    for (int j = 0; j < 4; ++j)
      bf[j] = *(const bfrag*)&Bl[(wn * 64 + j * 16 + lm) * PK + q * 8];
#pragma unroll
    for (int i = 0; i < 4; ++i)
#pragma unroll
      for (int j = 0; j < 4; ++j)
        acc[i][j] = __builtin_amdgcn_mfma_f32_16x16x32_bf16(af[i], bf[j], acc[i][j], 0, 0, 0);
  }

  // ---- v reduction across the 8 t-row groups (lane bits 0..2 of B waves) ----
  if (isB && mt == 0) {
#pragma unroll
    for (int m = 1; m <= 4; m <<= 1) {
      vacc4.x += __shfl_xor(vacc4.x, m);
      vacc4.y += __shfl_xor(vacc4.y, m);
      vacc4.z += __shfl_xor(vacc4.z, m);
      vacc4.w += __shfl_xor(vacc4.w, m);
    }
  }

  if (ATOMIC) {
    float* Mb = Mout + (size_t)bb * DMODEL * DMODEL;
#pragma unroll
    for (int i = 0; i < 4; ++i)
#pragma unroll
      for (int j = 0; j < 4; ++j)
#pragma unroll
        for (int r = 0; r < 4; ++r) {
          const int row = mt * TM + wm * 64 + i * 16 + q * 4 + r;
          const int col = nt * TN + wn * 64 + j * 16 + lm;
          atomAddF(&Mb[(size_t)row * DMODEL + col], acc[i][j][r]);
        }
    if (isB && mt == 0 && (lane & 7) == 0) {
      float* vp = &vout[bb * DMODEL + nt * TN + colB];
      atomAddF(vp + 0, vacc4.x); atomAddF(vp + 1, vacc4.y);
      atomAddF(vp + 2, vacc4.z); atomAddF(vp + 3, vacc4.w);
    }
  } else {
    float* Mp = Mout + (size_t)blk * (TM * TN);
#pragma unroll
    for (int i = 0; i < 4; ++i)
#pragma unroll
      for (int j = 0; j < 4; ++j)
#pragma unroll
        for (int r = 0; r < 4; ++r) {
          const int row = wm * 64 + i * 16 + q * 4 + r;    // local d'
          const int col = wn * 64 + j * 16 + lm;           // local d
          Mp[row * TN + col] = acc[i][j][r];
        }
    if (isB && mt == 0 && (lane & 7) == 0) {
      *(float4*)&vout[(size_t)(kt * NBATCH + bb) * DMODEL + nt * TN + colB] = vacc4;
    }
  }
}

// ---------------------------------------------------------------------------
// Reduce: Mred = sum_kt Mpart; vws = sum_kt vpart.  262144 threads.
// Partial layout matches gemm_m's blk = bb*(8NS) + kt*8 + (mt*4+nt),
// tile = 256x128 row-major.
// ---------------------------------------------------------------------------
template <int NS>
__global__ __launch_bounds__(256) void reduce_kernel(
    const float* __restrict__ Mpart, const float* __restrict__ vpart,
    float* __restrict__ Mred, float* __restrict__ vws)
{
  const int gid = blockIdx.x * 256 + threadIdx.x;    // one float4 each
  const int bb   = gid >> 16;            // 65536 float4 per batch
  const int rem  = gid & 65535;
  const int R    = rem >> 7;             // output row 0..511
  const int c128 = rem & 127;            // float4 col 0..127

  const int mt = R >> 8, r = R & 255;
  const int nt = c128 >> 5;
  const int cin = (c128 & 31) * 4;       // col within 128-wide tile

  const size_t tilesz = (size_t)TM * TN; // 32768
  const size_t base = ((size_t)bb * 8 * NS + (size_t)(mt * 4 + nt)) * tilesz
                    + (size_t)r * TN + cin;
  float4 s = {0.f, 0.f, 0.f, 0.f};
#pragma unroll
  for (int kt = 0; kt < NS; ++kt) {
    const float4 v = *(const float4*)&Mpart[base + (size_t)kt * 8 * tilesz];
    s.x += v.x; s.y += v.y; s.z += v.z; s.w += v.w;
  }
  *(float4*)&Mred[((size_t)bb * DMODEL + R) * DMODEL + c128 * 4] = s;

  if (gid < (NBATCH * DMODEL / 4)) {     // 512 threads: v reduction
    const int vb = gid >> 7;
    const int vc = (gid & 127) * 4;
    float4 vs = {0.f, 0.f, 0.f, 0.f};
#pragma unroll
    for (int kt = 0; kt < NS; ++kt) {
      const float4 v = *(const float4*)&vpart[(size_t)(kt * NBATCH + vb) * DMODEL + vc];
      vs.x += v.x; vs.y += v.y; vs.z += v.z; vs.w += v.w;
    }
    *(float4*)&vws[vb * DMODEL + vc] = vs;
  }
}

// ---------------------------------------------------------------------------
// Kernel 3: C[b][s][d] = sum_{d'} W[s][d'] Mred[b][d'][d] + bias[s]*v[b][d]
// 64x64 tiles, K=512, 16 pipelined iters, plain stores. (Unchanged.)
// ---------------------------------------------------------------------------
__global__ __launch_bounds__(256) void gemm_c_kernel(
    const float* __restrict__ Wmat, const float* __restrict__ bias,
    const float* __restrict__ Mred, const float* __restrict__ vws,
    float* __restrict__ out)
{
  __shared__ short Wl[64 * PKC];
  __shared__ short Ml[64 * PKC];

  const int blk = blockIdx.x;          // grid = 4 * 8 * 8 = 256
  const int ntc = blk & 7;
  const int mtc = (blk >> 3) & 7;
  const int bb  = blk >> 6;

  const int tid  = threadIdx.x;
  const bool isM = (tid >= 128);
  const int hid  = tid & 127;
  const int arow = hid & 63;           // W-half
  const int ahalf = (hid >> 6) * 16;
  const int mcol4 = (hid & 15) * 4;    // M-half
  const int mrow4 = (hid >> 4) * 4;

  const int wv   = tid >> 6;
  const int lane = tid & 63;
  const int lm   = lane & 15, q = lane >> 4;

  const float* Mb = Mred + (size_t)bb * DMODEL * DMODEL;

  facc acc[4];
#pragma unroll
  for (int j = 0; j < 4; ++j) acc[j] = (facc){0.f, 0.f, 0.f, 0.f};

  float4 cur[4];
  if (!isM) {
    const float* p = &Wmat[(size_t)(mtc * 64 + arow) * DMODEL + ahalf];
#pragma unroll
    for (int r = 0; r < 4; ++r) cur[r] = *(const float4*)(p + r * 4);
  } else {
    const float* p = Mb + (size_t)mrow4 * DMODEL + ntc * 64 + mcol4;
#pragma unroll
    for (int r = 0; r < 4; ++r) cur[r] = *(const float4*)(p + (size_t)r * DMODEL);
  }

  for (int k0 = 0; k0 < DMODEL; k0 += CBK) {
    uint4 pw0, pw1;
    uint2 pm[4];
    if (!isM) {
      pw0.x = pk2(cur[0].x, cur[0].y); pw0.y = pk2(cur[0].z, cur[0].w);
      pw0.z = pk2(cur[1].x, cur[1].y); pw0.w = pk2(cur[1].z, cur[1].w);
      pw1.x = pk2(cur[2].x, cur[2].y); pw1.y = pk2(cur[2].z, cur[2].w);
      pw1.z = pk2(cur[3].x, cur[3].y); pw1.w = pk2(cur[3].z, cur[3].w);
    } else {
#pragma unroll
      for (int c = 0; c < 4; ++c) {
        pm[c].x = pk2(selc(cur[0], c), selc(cur[1], c));
        pm[c].y = pk2(selc(cur[2], c), selc(cur[3], c));
      }
    }

    if (k0 + CBK < DMODEL) {
      if (!isM) {
        const float* p = &Wmat[(size_t)(mtc * 64 + arow) * DMODEL + k0 + CBK + ahalf];
#pragma unroll
        for (int r = 0; r < 4; ++r) cur[r] = *(const float4*)(p + r * 4);
      } else {
        const float* p = Mb + (size_t)(k0 + CBK + mrow4) * DMODEL + ntc * 64 + mcol4;
#pragma unroll
        for (int r = 0; r < 4; ++r) cur[r] = *(const float4*)(p + (size_t)r * DMODEL);
      }
    }

    __syncthreads();
    if (!isM) {
      *(uint4*)&Wl[arow * PKC + ahalf]     = pw0;
      *(uint4*)&Wl[arow * PKC + ahalf + 8] = pw1;
    } else {
#pragma unroll
      for (int c = 0; c < 4; ++c)
        *(uint2*)&Ml[(mcol4 + c) * PKC + mrow4] = pm[c];
    }
    __syncthreads();

    bfrag af, bf[4];
    af = *(const bfrag*)&Wl[(wv * 16 + lm) * PKC + q * 8];
#pragma unroll
    for (int j = 0; j < 4; ++j)
      bf[j] = *(const bfrag*)&Ml[(j * 16 + lm) * PKC + q * 8];
#pragma unroll
    for (int j = 0; j < 4; ++j)
      acc[j] = __builtin_amdgcn_mfma_f32_16x16x32_bf16(af, bf[j], acc[j], 0, 0, 0);
  }

#pragma unroll
  for (int j = 0; j < 4; ++j)
#pragma unroll
    for (int r = 0; r < 4; ++r) {
      const int row = mtc * 64 + wv * 16 + q * 4 + r;   // s
      const int col = ntc * 64 + j * 16 + lm;           // d
      out[((size_t)bb * DMODEL + row) * DMODEL + col] =
          acc[j][r] + bias[row] * vws[bb * DMODEL + col];
    }
}

// ---------------------------------------------------------------------------
extern "C" void kernel_launch(void* const* d_in, const int* in_sizes, int n_in,
                              void* d_out, int out_size, void* d_ws, size_t ws_size,
                              hipStream_t stream) {
  const float* h    = (const float*)d_in[0];   // (4, 8192, 512) fp32
  const float* e    = (const float*)d_in[1];   // (4, 8192, 512) fp32
  const float* Wmat = (const float*)d_in[2];   // (512, 512) fp32
  const float* bias = (const float*)d_in[3];   // (512,) fp32
  float* out = (float*)d_out;                  // (4, 512, 512) fp32

  float* Mred  = (float*)((char*)d_ws + MRED_OFF);
  float* vws   = (float*)((char*)d_ws + VWS_OFF);
  float* Mpart = (float*)((char*)d_ws + MPART_OFF);

  constexpr int NS = 16;                       // grid 512 = 2 blocks/CU
  if (ws_size >= ws_need(NS)) {
    float* vpart = Mpart + mpart_elems(NS);
    gemm_m_kernel<NS, false><<<NBATCH * NS * 8, 512, 0, stream>>>(h, e, Mpart, vpart);
    reduce_kernel<NS><<<1024, 256, 0, stream>>>(Mpart, vpart, Mred, vws);
  } else {
    hipMemsetAsync(d_ws, 0, VWS_OFF + (size_t)NBATCH * DMODEL * 4, stream);
    gemm_m_kernel<NS, true><<<NBATCH * NS * 8, 512, 0, stream>>>(h, e, Mred, vws);
  }
  gemm_c_kernel<<<NBATCH * 64, 256, 0, stream>>>(Wmat, bias, Mred, vws, out);
}